// Round 7
// baseline (105.337 us; speedup 1.0000x reference)
//
#include <hip/hip_runtime.h>

static constexpr int B_ = 64;
static constexpr int L_ = 1 << 20;
static constexpr int OUT_LEN = 2 * (L_ >> 2) - 1; // 524287 (odd!)

__device__ __forceinline__ float dot4(const float4& v, float t0, float t1, float t2, float t3) {
    return fmaf(v.x, t0, fmaf(v.y, t1, fmaf(v.z, t2, v.w * t3)));
}

// v += dpp(v) on the VALU pipe. old=0 so masked-off rows contribute +0.
template<int CTRL, int RM>
__device__ __forceinline__ float dpp_add(float v) {
    int t = __builtin_amdgcn_update_dpp(0, __builtin_bit_cast(int, v), CTRL, RM, 0xF, true);
    return v + __builtin_bit_cast(float, t);
}

// Segmented sum over groups of M consecutive lanes; result in LAST lane of group.
template<int M>
__device__ __forceinline__ float seg_reduce(float v) {
    if constexpr (M >= 2)  v = dpp_add<0x111, 0xF>(v);  // row_shr:1
    if constexpr (M >= 4)  v = dpp_add<0x112, 0xF>(v);  // row_shr:2
    if constexpr (M >= 8)  v = dpp_add<0x114, 0xF>(v);  // row_shr:4
    if constexpr (M >= 16) v = dpp_add<0x118, 0xF>(v);  // row_shr:8
    if constexpr (M >= 32) v = dpp_add<0x142, 0xA>(v);  // row_bcast15
    if constexpr (M >= 64) v = dpp_add<0x143, 0xC>(v);  // row_bcast31
    return v;
}

// Output-staging LDS layout per block (4 chunks): s2:[0,1024) s3:[1024,1536)
// s4:[1536,1792) s5:[1792,1920) s6:[1920,1984) s7:[1984,2016) s8:[2016,2032)
// s9:[2032,2040) s10:[2040,2044)
__host__ __device__ constexpr int lds_base(int S) { return S == 2 ? 0 : 2048 - (8192 >> S); }

// Compute scale S for one chunk; taps from LDS (wlds), stage results into LDS.
template<int S>
__device__ __forceinline__ void scale_stage(const float4& v0, const float4& v1,
                                            const float4& v2, const float4& v3,
                                            const float* __restrict__ wlds,
                                            const float* __restrict__ bias,
                                            float* __restrict__ lds, int cc, int lane) {
    constexpr int w = 1 << S;
    constexpr int m = w >> 2;
    const float4 tp = *reinterpret_cast<const float4*>(wlds + (w - 1) + ((lane & (m - 1)) << 2));
    float p0 = seg_reduce<m>(dot4(v0, tp.x, tp.y, tp.z, tp.w));
    float p1 = seg_reduce<m>(dot4(v1, tp.x, tp.y, tp.z, tp.w));
    float p2 = seg_reduce<m>(dot4(v2, tp.x, tp.y, tp.z, tp.w));
    float p3 = seg_reduce<m>(dot4(v3, tp.x, tp.y, tp.z, tp.w));
    if ((lane & (m - 1)) == (m - 1)) {
        constexpr int per = 1024 >> S;   // outputs per chunk
        constexpr int sps = 256 >> S;    // stride between p_r within a chunk
        const int j = lane >> (S - 2);
        const float bs = bias[S - 1];
        float* p = lds + lds_base(S) + cc * per + j;
        p[0      ] = p0 + bs;
        p[    sps] = p1 + bs;
        p[2 * sps] = p2 + bs;
        p[3 * sps] = p3 + bs;
    }
}

// Write one region's block-run [A, A+N) as: scalar head (to 16B alignment),
// dense aligned dwordx4 body, scalar tail. Alignment from ABSOLUTE index.
template<int S>
__device__ __forceinline__ void write_region(float* __restrict__ out, size_t rowbase, int c0,
                                             const float* __restrict__ lds, int t) {
    constexpr int N  = 4096 >> S;        // dwords per block-run (4 chunks)
    constexpr int LB = lds_base(S);
    const size_t A = rowbase + (size_t)((L_ >> S) - 1) + (size_t)c0 * (1024 >> S);
    float* gp = out + A;
    const int h = (int)((4 - (A & 3)) & 3);   // scalar head dwords
    const int K = (N - h) >> 2;               // aligned float4 stores
    const int r = N - h - 4 * K;              // scalar tail dwords
    if (t < K) {
        const int i = h + 4 * t;
        float4 v = make_float4(lds[LB + i], lds[LB + i + 1], lds[LB + i + 2], lds[LB + i + 3]);
        *reinterpret_cast<float4*>(gp + i) = v;
    }
    if (t < h) gp[t] = lds[LB + t];
    if (t < r) gp[N - r + t] = lds[LB + N - r + t];
}

__global__ __launch_bounds__(256) void multiscale_conv(
    const float* __restrict__ data,
    const float* __restrict__ weights,
    const float* __restrict__ bias,
    float* __restrict__ out)
{
    __shared__ float lds[2044];    // output staging
    __shared__ float wlds[2047];   // all taps, LDS-resident (DS pipe is otherwise idle)

    const int tid  = threadIdx.x;
    const int lane = tid & 63;
    const int cc   = tid >> 6;                 // chunk-in-block, 0..3

    // XCD-contiguous swizzle (gridDim.x = 16384, multiple of 8 -> bijective)
    const int nblk = gridDim.x;
    const int bid  = blockIdx.x;
    const int sw   = (bid & 7) * (nblk >> 3) + (bid >> 3);

    const int g0 = sw * 4;                     // block's first chunk (4 | 1024 -> same row)
    const int g  = g0 + cc;
    const int b  = g >> 10;                    // row
    const int c0 = g0 & 1023;                  // block's first chunk within row

    const float4* dp = reinterpret_cast<const float4*>(data + (size_t)b * L_ + (size_t)(g & 1023) * 1024);
    const float4 v0 = dp[lane];
    const float4 v1 = dp[lane + 64];
    const float4 v2 = dp[lane + 128];
    const float4 v3 = dp[lane + 192];

    // stage all taps into LDS (once per block; weights are L2-resident)
#pragma unroll
    for (int i = 0; i < 8; ++i) {
        const int j = tid + 256 * i;
        if (j < 2047) wlds[j] = weights[j];
    }
    __syncthreads();

    const size_t rowbase = (size_t)b * OUT_LEN;

    // compute + stage all scales (taps via ds_read)
    scale_stage<2>(v0, v1, v2, v3, wlds, bias, lds, cc, lane);
    scale_stage<3>(v0, v1, v2, v3, wlds, bias, lds, cc, lane);
    scale_stage<4>(v0, v1, v2, v3, wlds, bias, lds, cc, lane);
    scale_stage<5>(v0, v1, v2, v3, wlds, bias, lds, cc, lane);
    scale_stage<6>(v0, v1, v2, v3, wlds, bias, lds, cc, lane);
    scale_stage<7>(v0, v1, v2, v3, wlds, bias, lds, cc, lane);
    scale_stage<8>(v0, v1, v2, v3, wlds, bias, lds, cc, lane);

    // s = 9 (w = 512): two segments per chunk
    {
        const float4 ta = *reinterpret_cast<const float4*>(wlds + 511 + (lane << 2));
        const float4 tb = *reinterpret_cast<const float4*>(wlds + 511 + 256 + (lane << 2));
        float p = dot4(v0, ta.x, ta.y, ta.z, ta.w) + dot4(v1, tb.x, tb.y, tb.z, tb.w);
        float q = dot4(v2, ta.x, ta.y, ta.z, ta.w) + dot4(v3, tb.x, tb.y, tb.z, tb.w);
        p = seg_reduce<64>(p);
        q = seg_reduce<64>(q);
        if (lane == 63) {
            const float bs = bias[8];
            lds[2032 + 2 * cc    ] = p + bs;
            lds[2032 + 2 * cc + 1] = q + bs;
        }
    }

    // s = 10 (w = 1024): one segment per chunk
    {
        const float4 u0 = *reinterpret_cast<const float4*>(wlds + 1023 + (lane << 2));
        const float4 u1 = *reinterpret_cast<const float4*>(wlds + 1023 + 256 + (lane << 2));
        const float4 u2 = *reinterpret_cast<const float4*>(wlds + 1023 + 512 + (lane << 2));
        const float4 u3 = *reinterpret_cast<const float4*>(wlds + 1023 + 768 + (lane << 2));
        float p = dot4(v0, u0.x, u0.y, u0.z, u0.w);
        p      += dot4(v1, u1.x, u1.y, u1.z, u1.w);
        p      += dot4(v2, u2.x, u2.y, u2.z, u2.w);
        p      += dot4(v3, u3.x, u3.y, u3.z, u3.w);
        p = seg_reduce<64>(p);
        if (lane == 63) lds[2040 + cc] = p + bias[9];
    }

    __syncthreads();

    // aligned block-level write-out
    write_region<2>(out, rowbase, c0, lds, tid);
    write_region<3>(out, rowbase, c0, lds, tid);
    write_region<4>(out, rowbase, c0, lds, tid);
    write_region<5>(out, rowbase, c0, lds, tid);
    write_region<6>(out, rowbase, c0, lds, tid);
    write_region<7>(out, rowbase, c0, lds, tid);
    write_region<8>(out, rowbase, c0, lds, tid);
    if (tid < 8) out[rowbase + 2047 + (size_t)c0 * 2 + tid] = lds[2032 + tid];
    if (tid < 4) out[rowbase + 1023 + (size_t)c0     + tid] = lds[2040 + tid];

    // out[:, 0:1023) must be zero (harness poisons d_out); aligned fill
    if (c0 == 0) {
        float* gp = out + rowbase;
        const int h = (int)((4 - (rowbase & 3)) & 3);
        const int K = (1023 - h) >> 2;                 // <= 255
        const int r = 1023 - h - 4 * K;
        if (tid < h) gp[tid] = 0.0f;
        if (tid < K) *reinterpret_cast<float4*>(gp + h + 4 * tid) = make_float4(0.f, 0.f, 0.f, 0.f);
        if (tid < r) gp[1023 - r + tid] = 0.0f;
    }
}

extern "C" void kernel_launch(void* const* d_in, const int* in_sizes, int n_in,
                              void* d_out, int out_size, void* d_ws, size_t ws_size,
                              hipStream_t stream) {
    const float* data    = (const float*)d_in[0];
    const float* weights = (const float*)d_in[1];
    const float* bias    = (const float*)d_in[2];
    float* out = (float*)d_out;

    const int n_chunks = B_ * (L_ / 1024);      // 65536 chunks
    dim3 grid(n_chunks / 4);                    // 16384 blocks x 4 waves
    dim3 block(256);
    multiscale_conv<<<grid, block, 0, stream>>>(data, weights, bias, out);
}

// Round 9
// 83.768 us; speedup vs baseline: 1.2575x; 1.2575x over previous
//
#include <hip/hip_runtime.h>

static constexpr int B_ = 64;
static constexpr int L_ = 1 << 20;
static constexpr int OUT_LEN = 2 * (L_ >> 2) - 1; // 524287 (odd!)

typedef float f32x4 __attribute__((ext_vector_type(4)));   // native vector type for nt builtins

__device__ __forceinline__ float dot4(const float4& v, float t0, float t1, float t2, float t3) {
    return fmaf(v.x, t0, fmaf(v.y, t1, fmaf(v.z, t2, v.w * t3)));
}

// v += dpp(v) on the VALU pipe. old=0 so masked-off rows contribute +0.
template<int CTRL, int RM>
__device__ __forceinline__ float dpp_add(float v) {
    int t = __builtin_amdgcn_update_dpp(0, __builtin_bit_cast(int, v), CTRL, RM, 0xF, true);
    return v + __builtin_bit_cast(float, t);
}

// Segmented sum over groups of M consecutive lanes; result in LAST lane of group.
template<int M>
__device__ __forceinline__ float seg_reduce(float v) {
    if constexpr (M >= 2)  v = dpp_add<0x111, 0xF>(v);  // row_shr:1
    if constexpr (M >= 4)  v = dpp_add<0x112, 0xF>(v);  // row_shr:2
    if constexpr (M >= 8)  v = dpp_add<0x114, 0xF>(v);  // row_shr:4
    if constexpr (M >= 16) v = dpp_add<0x118, 0xF>(v);  // row_shr:8
    if constexpr (M >= 32) v = dpp_add<0x142, 0xA>(v);  // row_bcast15
    if constexpr (M >= 64) v = dpp_add<0x143, 0xC>(v);  // row_bcast31
    return v;
}

// Output-staging LDS layout per block (4 chunks): s2:[0,1024) s3:[1024,1536)
// s4:[1536,1792) s5:[1792,1920) s6:[1920,1984) s7:[1984,2016) s8:[2016,2032)
// s9:[2032,2040) s10:[2040,2044)
__host__ __device__ constexpr int lds_base(int S) { return S == 2 ? 0 : 2048 - (8192 >> S); }

// Compute scale S for one chunk and stage results into LDS. Taps via cached
// global loads (L1-resident; proven non-binding by R7's ablation).
template<int S>
__device__ __forceinline__ void scale_stage(const float4& v0, const float4& v1,
                                            const float4& v2, const float4& v3,
                                            const float* __restrict__ weights,
                                            const float* __restrict__ bias,
                                            float* __restrict__ lds, int cc, int lane) {
    constexpr int w = 1 << S;
    constexpr int m = w >> 2;
    const float* tp = weights + (w - 1) + ((lane & (m - 1)) << 2);
    const float t0 = tp[0], t1 = tp[1], t2 = tp[2], t3 = tp[3];
    float p0 = seg_reduce<m>(dot4(v0, t0, t1, t2, t3));
    float p1 = seg_reduce<m>(dot4(v1, t0, t1, t2, t3));
    float p2 = seg_reduce<m>(dot4(v2, t0, t1, t2, t3));
    float p3 = seg_reduce<m>(dot4(v3, t0, t1, t2, t3));
    if ((lane & (m - 1)) == (m - 1)) {
        constexpr int per = 1024 >> S;   // outputs per chunk
        constexpr int sps = 256 >> S;    // stride between p_r within a chunk
        const int j = lane >> (S - 2);
        const float bs = bias[S - 1];
        float* p = lds + lds_base(S) + cc * per + j;
        p[0      ] = p0 + bs;
        p[    sps] = p1 + bs;
        p[2 * sps] = p2 + bs;
        p[3 * sps] = p3 + bs;
    }
}

// Write one region's block-run [A, A+N): scalar head (to 16B alignment), dense
// aligned dwordx4 body, scalar tail — all NONTEMPORAL (streaming, no reuse).
template<int S>
__device__ __forceinline__ void write_region(float* __restrict__ out, size_t rowbase, int c0,
                                             const float* __restrict__ lds, int t) {
    constexpr int N  = 4096 >> S;        // dwords per block-run (4 chunks)
    constexpr int LB = lds_base(S);
    const size_t A = rowbase + (size_t)((L_ >> S) - 1) + (size_t)c0 * (1024 >> S);
    float* gp = out + A;
    const int h = (int)((4 - (A & 3)) & 3);   // scalar head dwords
    const int K = (N - h) >> 2;               // aligned float4 stores
    const int r = N - h - 4 * K;              // scalar tail dwords
    if (t < K) {
        const int i = h + 4 * t;
        f32x4 v = { lds[LB + i], lds[LB + i + 1], lds[LB + i + 2], lds[LB + i + 3] };
        __builtin_nontemporal_store(v, reinterpret_cast<f32x4*>(gp + i));
    }
    if (t < h) __builtin_nontemporal_store(lds[LB + t], gp + t);
    if (t < r) __builtin_nontemporal_store(lds[LB + N - r + t], gp + N - r + t);
}

__global__ __launch_bounds__(256) void multiscale_conv(
    const float* __restrict__ data,
    const float* __restrict__ weights,
    const float* __restrict__ bias,
    float* __restrict__ out)
{
    __shared__ float lds[2044];

    const int tid  = threadIdx.x;
    const int lane = tid & 63;
    const int cc   = tid >> 6;                 // chunk-in-block, 0..3

    // XCD-contiguous swizzle (gridDim.x = 16384, multiple of 8 -> bijective)
    const int nblk = gridDim.x;
    const int bid  = blockIdx.x;
    const int sw   = (bid & 7) * (nblk >> 3) + (bid >> 3);

    const int g0 = sw * 4;                     // block's first chunk (4 | 1024 -> same row)
    const int g  = g0 + cc;
    const int b  = g >> 10;                    // row
    const int c0 = g0 & 1023;                  // block's first chunk within row

    const f32x4* dp = reinterpret_cast<const f32x4*>(data + (size_t)b * L_ + (size_t)(g & 1023) * 1024);
    // streaming data: nontemporal loads (no reuse -> don't allocate in L2/L3)
    const float4 v0 = __builtin_bit_cast(float4, __builtin_nontemporal_load(dp + lane));
    const float4 v1 = __builtin_bit_cast(float4, __builtin_nontemporal_load(dp + lane + 64));
    const float4 v2 = __builtin_bit_cast(float4, __builtin_nontemporal_load(dp + lane + 128));
    const float4 v3 = __builtin_bit_cast(float4, __builtin_nontemporal_load(dp + lane + 192));

    const size_t rowbase = (size_t)b * OUT_LEN;

    // compute + stage all scales
    scale_stage<2>(v0, v1, v2, v3, weights, bias, lds, cc, lane);
    scale_stage<3>(v0, v1, v2, v3, weights, bias, lds, cc, lane);
    scale_stage<4>(v0, v1, v2, v3, weights, bias, lds, cc, lane);
    scale_stage<5>(v0, v1, v2, v3, weights, bias, lds, cc, lane);
    scale_stage<6>(v0, v1, v2, v3, weights, bias, lds, cc, lane);
    scale_stage<7>(v0, v1, v2, v3, weights, bias, lds, cc, lane);
    scale_stage<8>(v0, v1, v2, v3, weights, bias, lds, cc, lane);

    // s = 9 (w = 512): two segments per chunk
    {
        const float* ta = weights + 511 + (lane << 2);
        const float* tb = ta + 256;
        float p = dot4(v0, ta[0], ta[1], ta[2], ta[3]) + dot4(v1, tb[0], tb[1], tb[2], tb[3]);
        float q = dot4(v2, ta[0], ta[1], ta[2], ta[3]) + dot4(v3, tb[0], tb[1], tb[2], tb[3]);
        p = seg_reduce<64>(p);
        q = seg_reduce<64>(q);
        if (lane == 63) {
            const float bs = bias[8];
            lds[2032 + 2 * cc    ] = p + bs;
            lds[2032 + 2 * cc + 1] = q + bs;
        }
    }

    // s = 10 (w = 1024): one segment per chunk
    {
        const float* t = weights + 1023 + (lane << 2);
        const float4 u0 = *reinterpret_cast<const float4*>(t);
        const float4 u1 = *reinterpret_cast<const float4*>(t + 256);
        const float4 u2 = *reinterpret_cast<const float4*>(t + 512);
        const float4 u3 = *reinterpret_cast<const float4*>(t + 768);
        float p = dot4(v0, u0.x, u0.y, u0.z, u0.w);
        p      += dot4(v1, u1.x, u1.y, u1.z, u1.w);
        p      += dot4(v2, u2.x, u2.y, u2.z, u2.w);
        p      += dot4(v3, u3.x, u3.y, u3.z, u3.w);
        p = seg_reduce<64>(p);
        if (lane == 63) lds[2040 + cc] = p + bias[9];
    }

    __syncthreads();

    // aligned block-level nontemporal write-out
    write_region<2>(out, rowbase, c0, lds, tid);
    write_region<3>(out, rowbase, c0, lds, tid);
    write_region<4>(out, rowbase, c0, lds, tid);
    write_region<5>(out, rowbase, c0, lds, tid);
    write_region<6>(out, rowbase, c0, lds, tid);
    write_region<7>(out, rowbase, c0, lds, tid);
    write_region<8>(out, rowbase, c0, lds, tid);
    if (tid < 8) __builtin_nontemporal_store(lds[2032 + tid], out + rowbase + 2047 + (size_t)c0 * 2 + tid);
    if (tid < 4) __builtin_nontemporal_store(lds[2040 + tid], out + rowbase + 1023 + (size_t)c0 + tid);

    // out[:, 0:1023) must be zero (harness poisons d_out); aligned nt fill
    if (c0 == 0) {
        float* gp = out + rowbase;
        const int h = (int)((4 - (rowbase & 3)) & 3);
        const int K = (1023 - h) >> 2;                 // <= 255
        const int r = 1023 - h - 4 * K;
        if (tid < h) __builtin_nontemporal_store(0.0f, gp + tid);
        if (tid < K) {
            f32x4 z = { 0.f, 0.f, 0.f, 0.f };
            __builtin_nontemporal_store(z, reinterpret_cast<f32x4*>(gp + h + 4 * tid));
        }
        if (tid < r) __builtin_nontemporal_store(0.0f, gp + 1023 - r + tid);
    }
}

extern "C" void kernel_launch(void* const* d_in, const int* in_sizes, int n_in,
                              void* d_out, int out_size, void* d_ws, size_t ws_size,
                              hipStream_t stream) {
    const float* data    = (const float*)d_in[0];
    const float* weights = (const float*)d_in[1];
    const float* bias    = (const float*)d_in[2];
    float* out = (float*)d_out;

    const int n_chunks = B_ * (L_ / 1024);      // 65536 chunks
    dim3 grid(n_chunks / 4);                    // 16384 blocks x 4 waves
    dim3 block(256);
    multiscale_conv<<<grid, block, 0, stream>>>(data, weights, bias, out);
}

// Round 10
// 82.443 us; speedup vs baseline: 1.2777x; 1.0161x over previous
//
#include <hip/hip_runtime.h>

static constexpr int B_ = 64;
static constexpr int L_ = 1 << 20;
static constexpr int OUT_LEN = 2 * (L_ >> 2) - 1; // 524287 (odd!)

typedef float f32x4 __attribute__((ext_vector_type(4)));   // native vector type for nt builtins

__device__ __forceinline__ float dot4(const float4& v, float t0, float t1, float t2, float t3) {
    return fmaf(v.x, t0, fmaf(v.y, t1, fmaf(v.z, t2, v.w * t3)));
}

// v += dpp(v) on the VALU pipe. old=0 so masked-off rows contribute +0.
template<int CTRL, int RM>
__device__ __forceinline__ float dpp_add(float v) {
    int t = __builtin_amdgcn_update_dpp(0, __builtin_bit_cast(int, v), CTRL, RM, 0xF, true);
    return v + __builtin_bit_cast(float, t);
}

// Segmented sum over groups of M consecutive lanes; result in LAST lane of group.
template<int M>
__device__ __forceinline__ float seg_reduce(float v) {
    if constexpr (M >= 2)  v = dpp_add<0x111, 0xF>(v);  // row_shr:1
    if constexpr (M >= 4)  v = dpp_add<0x112, 0xF>(v);  // row_shr:2
    if constexpr (M >= 8)  v = dpp_add<0x114, 0xF>(v);  // row_shr:4
    if constexpr (M >= 16) v = dpp_add<0x118, 0xF>(v);  // row_shr:8
    if constexpr (M >= 32) v = dpp_add<0x142, 0xA>(v);  // row_bcast15
    if constexpr (M >= 64) v = dpp_add<0x143, 0xC>(v);  // row_bcast31
    return v;
}

// Output-staging LDS layout per block (4 chunks): s2:[0,1024) s3:[1024,1536)
// s4:[1536,1792) s5:[1792,1920) s6:[1920,1984) s7:[1984,2016) s8:[2016,2032)
// s9:[2032,2040) s10:[2040,2044)
__host__ __device__ constexpr int lds_base(int S) { return S == 2 ? 0 : 2048 - (8192 >> S); }

// Compute scale S for one chunk and stage results into LDS. Taps via cached
// global loads (L1-resident; proven non-binding by R7's ablation).
template<int S>
__device__ __forceinline__ void scale_stage(const float4& v0, const float4& v1,
                                            const float4& v2, const float4& v3,
                                            const float* __restrict__ weights,
                                            const float* __restrict__ bias,
                                            float* __restrict__ lds, int cc, int lane) {
    constexpr int w = 1 << S;
    constexpr int m = w >> 2;
    const float* tp = weights + (w - 1) + ((lane & (m - 1)) << 2);
    const float t0 = tp[0], t1 = tp[1], t2 = tp[2], t3 = tp[3];
    float p0 = seg_reduce<m>(dot4(v0, t0, t1, t2, t3));
    float p1 = seg_reduce<m>(dot4(v1, t0, t1, t2, t3));
    float p2 = seg_reduce<m>(dot4(v2, t0, t1, t2, t3));
    float p3 = seg_reduce<m>(dot4(v3, t0, t1, t2, t3));
    if ((lane & (m - 1)) == (m - 1)) {
        constexpr int per = 1024 >> S;   // outputs per chunk
        constexpr int sps = 256 >> S;    // stride between p_r within a chunk
        const int j = lane >> (S - 2);
        const float bs = bias[S - 1];
        float* p = lds + lds_base(S) + cc * per + j;
        p[0      ] = p0 + bs;
        p[    sps] = p1 + bs;
        p[2 * sps] = p2 + bs;
        p[3 * sps] = p3 + bs;
    }
}

// Write one region's block-run [A, A+N): scalar head (to 16B alignment), dense
// aligned dwordx4 body, scalar tail — CACHED stores (output fits L3; L2 merges).
template<int S>
__device__ __forceinline__ void write_region(float* __restrict__ out, size_t rowbase, int c0,
                                             const float* __restrict__ lds, int t) {
    constexpr int N  = 4096 >> S;        // dwords per block-run (4 chunks)
    constexpr int LB = lds_base(S);
    const size_t A = rowbase + (size_t)((L_ >> S) - 1) + (size_t)c0 * (1024 >> S);
    float* gp = out + A;
    const int h = (int)((4 - (A & 3)) & 3);   // scalar head dwords
    const int K = (N - h) >> 2;               // aligned float4 stores
    const int r = N - h - 4 * K;              // scalar tail dwords
    if (t < K) {
        const int i = h + 4 * t;
        float4 v = make_float4(lds[LB + i], lds[LB + i + 1], lds[LB + i + 2], lds[LB + i + 3]);
        *reinterpret_cast<float4*>(gp + i) = v;
    }
    if (t < h) gp[t] = lds[LB + t];
    if (t < r) gp[N - r + t] = lds[LB + N - r + t];
}

__global__ __launch_bounds__(256) void multiscale_conv(
    const float* __restrict__ data,
    const float* __restrict__ weights,
    const float* __restrict__ bias,
    float* __restrict__ out)
{
    __shared__ float lds[2044];

    const int tid  = threadIdx.x;
    const int lane = tid & 63;
    const int cc   = tid >> 6;                 // chunk-in-block, 0..3

    // XCD-contiguous swizzle (gridDim.x = 16384, multiple of 8 -> bijective)
    const int nblk = gridDim.x;
    const int bid  = blockIdx.x;
    const int sw   = (bid & 7) * (nblk >> 3) + (bid >> 3);

    const int g0 = sw * 4;                     // block's first chunk (4 | 1024 -> same row)
    const int g  = g0 + cc;
    const int b  = g >> 10;                    // row
    const int c0 = g0 & 1023;                  // block's first chunk within row

    const f32x4* dp = reinterpret_cast<const f32x4*>(data + (size_t)b * L_ + (size_t)(g & 1023) * 1024);
    // streaming data: nontemporal loads (no reuse -> never allocate, never evict)
    const float4 v0 = __builtin_bit_cast(float4, __builtin_nontemporal_load(dp + lane));
    const float4 v1 = __builtin_bit_cast(float4, __builtin_nontemporal_load(dp + lane + 64));
    const float4 v2 = __builtin_bit_cast(float4, __builtin_nontemporal_load(dp + lane + 128));
    const float4 v3 = __builtin_bit_cast(float4, __builtin_nontemporal_load(dp + lane + 192));

    const size_t rowbase = (size_t)b * OUT_LEN;

    // compute + stage all scales
    scale_stage<2>(v0, v1, v2, v3, weights, bias, lds, cc, lane);
    scale_stage<3>(v0, v1, v2, v3, weights, bias, lds, cc, lane);
    scale_stage<4>(v0, v1, v2, v3, weights, bias, lds, cc, lane);
    scale_stage<5>(v0, v1, v2, v3, weights, bias, lds, cc, lane);
    scale_stage<6>(v0, v1, v2, v3, weights, bias, lds, cc, lane);
    scale_stage<7>(v0, v1, v2, v3, weights, bias, lds, cc, lane);
    scale_stage<8>(v0, v1, v2, v3, weights, bias, lds, cc, lane);

    // s = 9 (w = 512): two segments per chunk
    {
        const float* ta = weights + 511 + (lane << 2);
        const float* tb = ta + 256;
        float p = dot4(v0, ta[0], ta[1], ta[2], ta[3]) + dot4(v1, tb[0], tb[1], tb[2], tb[3]);
        float q = dot4(v2, ta[0], ta[1], ta[2], ta[3]) + dot4(v3, tb[0], tb[1], tb[2], tb[3]);
        p = seg_reduce<64>(p);
        q = seg_reduce<64>(q);
        if (lane == 63) {
            const float bs = bias[8];
            lds[2032 + 2 * cc    ] = p + bs;
            lds[2032 + 2 * cc + 1] = q + bs;
        }
    }

    // s = 10 (w = 1024): one segment per chunk
    {
        const float* t = weights + 1023 + (lane << 2);
        const float4 u0 = *reinterpret_cast<const float4*>(t);
        const float4 u1 = *reinterpret_cast<const float4*>(t + 256);
        const float4 u2 = *reinterpret_cast<const float4*>(t + 512);
        const float4 u3 = *reinterpret_cast<const float4*>(t + 768);
        float p = dot4(v0, u0.x, u0.y, u0.z, u0.w);
        p      += dot4(v1, u1.x, u1.y, u1.z, u1.w);
        p      += dot4(v2, u2.x, u2.y, u2.z, u2.w);
        p      += dot4(v3, u3.x, u3.y, u3.z, u3.w);
        p = seg_reduce<64>(p);
        if (lane == 63) lds[2040 + cc] = p + bias[9];
    }

    __syncthreads();

    // aligned block-level cached write-out (output fits L3; lazy writeback)
    write_region<2>(out, rowbase, c0, lds, tid);
    write_region<3>(out, rowbase, c0, lds, tid);
    write_region<4>(out, rowbase, c0, lds, tid);
    write_region<5>(out, rowbase, c0, lds, tid);
    write_region<6>(out, rowbase, c0, lds, tid);
    write_region<7>(out, rowbase, c0, lds, tid);
    write_region<8>(out, rowbase, c0, lds, tid);
    if (tid < 8) out[rowbase + 2047 + (size_t)c0 * 2 + tid] = lds[2032 + tid];
    if (tid < 4) out[rowbase + 1023 + (size_t)c0     + tid] = lds[2040 + tid];

    // out[:, 0:1023) must be zero (harness poisons d_out); aligned fill
    if (c0 == 0) {
        float* gp = out + rowbase;
        const int h = (int)((4 - (rowbase & 3)) & 3);
        const int K = (1023 - h) >> 2;                 // <= 255
        const int r = 1023 - h - 4 * K;
        if (tid < h) gp[tid] = 0.0f;
        if (tid < K) *reinterpret_cast<float4*>(gp + h + 4 * tid) = make_float4(0.f, 0.f, 0.f, 0.f);
        if (tid < r) gp[1023 - r + tid] = 0.0f;
    }
}

extern "C" void kernel_launch(void* const* d_in, const int* in_sizes, int n_in,
                              void* d_out, int out_size, void* d_ws, size_t ws_size,
                              hipStream_t stream) {
    const float* data    = (const float*)d_in[0];
    const float* weights = (const float*)d_in[1];
    const float* bias    = (const float*)d_in[2];
    float* out = (float*)d_out;

    const int n_chunks = B_ * (L_ / 1024);      // 65536 chunks
    dim3 grid(n_chunks / 4);                    // 16384 blocks x 4 waves
    dim3 block(256);
    multiscale_conv<<<grid, block, 0, stream>>>(data, weights, bias, out);
}

// Round 11
// 81.964 us; speedup vs baseline: 1.2852x; 1.0058x over previous
//
#include <hip/hip_runtime.h>

static constexpr int B_ = 64;
static constexpr int L_ = 1 << 20;
static constexpr int OUT_LEN = 2 * (L_ >> 2) - 1; // 524287

typedef float f32x4 __attribute__((ext_vector_type(4)));   // native vector type for nt builtins

__device__ __forceinline__ float dot4(const float4& v, float t0, float t1, float t2, float t3) {
    return fmaf(v.x, t0, fmaf(v.y, t1, fmaf(v.z, t2, v.w * t3)));
}

// v += dpp(v) on the VALU pipe. old=0 so masked-off rows contribute +0.
template<int CTRL, int RM>
__device__ __forceinline__ float dpp_add(float v) {
    int t = __builtin_amdgcn_update_dpp(0, __builtin_bit_cast(int, v), CTRL, RM, 0xF, true);
    return v + __builtin_bit_cast(float, t);
}

// Segmented sum over groups of M consecutive lanes; result in LAST lane of group.
template<int M>
__device__ __forceinline__ float seg_reduce(float v) {
    if constexpr (M >= 2)  v = dpp_add<0x111, 0xF>(v);  // row_shr:1
    if constexpr (M >= 4)  v = dpp_add<0x112, 0xF>(v);  // row_shr:2
    if constexpr (M >= 8)  v = dpp_add<0x114, 0xF>(v);  // row_shr:4
    if constexpr (M >= 16) v = dpp_add<0x118, 0xF>(v);  // row_shr:8
    if constexpr (M >= 32) v = dpp_add<0x142, 0xA>(v);  // row_bcast15
    if constexpr (M >= 64) v = dpp_add<0x143, 0xC>(v);  // row_bcast31
    return v;
}

template<int S>
__device__ __forceinline__ void do_scale(const float4& v0, const float4& v1,
                                         const float4& v2, const float4& v3,
                                         const float* __restrict__ weights,
                                         const float* __restrict__ bias,
                                         float* __restrict__ orow, int c, int lane) {
    constexpr int w = 1 << S;
    constexpr int m = w >> 2;
    const float* tp = weights + (w - 1) + ((lane & (m - 1)) << 2);
    const float t0 = tp[0], t1 = tp[1], t2 = tp[2], t3 = tp[3];
    float p0 = seg_reduce<m>(dot4(v0, t0, t1, t2, t3));
    float p1 = seg_reduce<m>(dot4(v1, t0, t1, t2, t3));
    float p2 = seg_reduce<m>(dot4(v2, t0, t1, t2, t3));
    float p3 = seg_reduce<m>(dot4(v3, t0, t1, t2, t3));
    if ((lane & (m - 1)) == (m - 1)) {
        constexpr int base = (L_ >> S) - 1;
        constexpr int sps  = 256 >> S;
        const int seg = c * (1024 >> S) + (lane >> (S - 2));
        const float bs = bias[S - 1];
        orow[base + seg          ] = p0 + bs;
        orow[base + seg +     sps] = p1 + bs;
        orow[base + seg + 2 * sps] = p2 + bs;
        orow[base + seg + 3 * sps] = p3 + bs;
    }
}

__global__ __launch_bounds__(256) void multiscale_conv(
    const float* __restrict__ data,
    const float* __restrict__ weights,
    const float* __restrict__ bias,
    float* __restrict__ out)
{
    const int lane = threadIdx.x & 63;
    const int wv   = threadIdx.x >> 6;

    // XCD-contiguous swizzle (gridDim.x = 16384, multiple of 8 -> bijective)
    const int nblk = gridDim.x;
    const int bid  = blockIdx.x;
    const int sw   = (bid & 7) * (nblk >> 3) + (bid >> 3);

    const int g = sw * 4 + wv;            // chunk id (4 waves/block, 1 chunk/wave)
    const int b = g >> 10;                // row
    const int c = g & 1023;               // chunk within row

    const f32x4* dp = reinterpret_cast<const f32x4*>(data + (size_t)b * L_ + (size_t)c * 1024);
    // streaming data: nontemporal loads (no reuse -> never allocate, never evict)
    const float4 v0 = __builtin_bit_cast(float4, __builtin_nontemporal_load(dp + lane));
    const float4 v1 = __builtin_bit_cast(float4, __builtin_nontemporal_load(dp + lane + 64));
    const float4 v2 = __builtin_bit_cast(float4, __builtin_nontemporal_load(dp + lane + 128));
    const float4 v3 = __builtin_bit_cast(float4, __builtin_nontemporal_load(dp + lane + 192));

    float* orow = out + (size_t)b * OUT_LEN;

    // out[:, 0:1023) must be zero (harness poisons d_out)
    if (c == 0) {
        for (int j = lane; j < 1023; j += 64) orow[j] = 0.0f;
    }

    // per-wave direct writes, no barrier, no LDS: stores interleave with compute
    do_scale<2>(v0, v1, v2, v3, weights, bias, orow, c, lane);
    do_scale<3>(v0, v1, v2, v3, weights, bias, orow, c, lane);
    do_scale<4>(v0, v1, v2, v3, weights, bias, orow, c, lane);
    do_scale<5>(v0, v1, v2, v3, weights, bias, orow, c, lane);
    do_scale<6>(v0, v1, v2, v3, weights, bias, orow, c, lane);
    do_scale<7>(v0, v1, v2, v3, weights, bias, orow, c, lane);
    do_scale<8>(v0, v1, v2, v3, weights, bias, orow, c, lane);

    // s = 9 (w = 512): two segments per chunk
    {
        const float* ta = weights + 511 + (lane << 2);
        const float* tb = ta + 256;
        float p = dot4(v0, ta[0], ta[1], ta[2], ta[3]) + dot4(v1, tb[0], tb[1], tb[2], tb[3]);
        float q = dot4(v2, ta[0], ta[1], ta[2], ta[3]) + dot4(v3, tb[0], tb[1], tb[2], tb[3]);
        p = seg_reduce<64>(p);
        q = seg_reduce<64>(q);
        if (lane == 63) {
            const float bs = bias[8];
            orow[((L_ >> 9) - 1) + 2 * c    ] = p + bs;
            orow[((L_ >> 9) - 1) + 2 * c + 1] = q + bs;
        }
    }

    // s = 10 (w = 1024): one segment per chunk
    {
        const float* t = weights + 1023 + (lane << 2);
        float p = dot4(v0, t[0],   t[1],   t[2],   t[3]);
        p      += dot4(v1, t[256], t[257], t[258], t[259]);
        p      += dot4(v2, t[512], t[513], t[514], t[515]);
        p      += dot4(v3, t[768], t[769], t[770], t[771]);
        p = seg_reduce<64>(p);
        if (lane == 63) orow[((L_ >> 10) - 1) + c] = p + bias[9];
    }
}

extern "C" void kernel_launch(void* const* d_in, const int* in_sizes, int n_in,
                              void* d_out, int out_size, void* d_ws, size_t ws_size,
                              hipStream_t stream) {
    const float* data    = (const float*)d_in[0];
    const float* weights = (const float*)d_in[1];
    const float* bias    = (const float*)d_in[2];
    float* out = (float*)d_out;

    const int n_chunks = B_ * (L_ / 1024);      // 65536 chunks
    dim3 grid(n_chunks / 4);                    // 16384 blocks x 4 waves, 1 chunk/wave
    dim3 block(256);
    multiscale_conv<<<grid, block, 0, stream>>>(data, weights, bias, out);
}